// Round 16
// baseline (33.955 us; speedup 1.0000x reference)
//
#include <hip/hip_runtime.h>

// logits: [E=4, B=8192, C=1000] f32 (131 MB, memory-bound), target: [B] i32,
// out: [E] f32.  loss[e] = (1/(B*C)) * sum_c |colsum(logits[e])[c] - hist(target)[c]|
//
// Measured structure decisions:
//  - coop grid.sync: ~100us/sync (R6) -> never.
//  - ticket/fence single-dispatch handoff: nondeterministic (R8 tripwire) -> never.
//  - EACH extra dispatch costs ~4-6us (R11) -> exactly 2 dispatches.
//  - hist in colsum block 0 serializes (R10) -> dedicated extra block.
//  - partial rows cost tail time (R7 vs R14) -> keep 256 rows (1 MB).
//  - barriers must be block-uniform (R12 NaN); wave-granular early-exit before
//    any barrier is legal (hist block below: waves 4-15 exit, waves 0-3 sync).
//  - occupancy exhausted: 8 waves/CU (R14, 29.1) vs 16 waves/CU (R15, 28.5).
//  - R16 fix: 1024-thr hist block monopolized half a CU next to one colsum
//    block, gating dispatch 1's tail -> shrink hist to 4 waves (256 thr) so it
//    fits in any CU's spare wave slots.
constexpr int E_  = 4;
constexpr int B_  = 8192;
constexpr int C_  = 1000;
constexpr int CQ_ = C_ / 4;             // 250 float4 column-quads
constexpr int NB_ = 128;                // batch rows per colsum block
constexpr int CREWS_ = 4;               // 250-lane crews per block
constexpr int RPC_   = NB_ / CREWS_;    // 32 rows per crew
constexpr int NBLK_  = E_ * B_ / NB_;   // 256 colsum blocks (1/CU, 16 waves/CU)
constexpr int RPE_   = B_ / NB_;        // 64 partial rows per exit
constexpr int RG_    = 4;               // row-groups in finalize
constexpr int RPG_   = RPE_ / RG_;      // 16 rows per row-group

// ws: partial[NBLK_][C_] f32 | counts[C_] f32
constexpr size_t PARTIAL_BYTES = (size_t)NBLK_ * C_ * sizeof(float); // 1,024,000
constexpr size_t COUNTS_OFF    = PARTIAL_BYTES;

// ---- dispatch 1 (257 blocks x 1024): 256 colsum blocks + 1 small hist block -
__global__ __launch_bounds__(1024) void colsum_hist(
        const float* __restrict__ logits, const int* __restrict__ target,
        float* __restrict__ partial, float* __restrict__ counts) {
    const int b = blockIdx.x, t = threadIdx.x;

    if (b < NBLK_) {
        __shared__ float4 comb[CREWS_ - 1][CQ_];
        const int q = t % CQ_;
        const int h = t / CQ_;
        float4 acc = make_float4(0.f, 0.f, 0.f, 0.f);
        if (h < CREWS_) {
            const float4* base = reinterpret_cast<const float4*>(logits)
                               + (size_t)(b * NB_ + h * RPC_) * CQ_ + q;
            #pragma unroll 8
            for (int r = 0; r < RPC_; ++r) {
                float4 v = base[(size_t)r * CQ_];
                acc.x += v.x; acc.y += v.y; acc.z += v.z; acc.w += v.w;
            }
        }
        if (h >= 1 && h < CREWS_) comb[h - 1][q] = acc;
        __syncthreads();                 // single block-uniform barrier
        if (h == 0) {
            #pragma unroll
            for (int j = 0; j < CREWS_ - 1; ++j) {
                float4 o = comb[j][q];
                acc.x += o.x; acc.y += o.y; acc.z += o.z; acc.w += o.w;
            }
            reinterpret_cast<float4*>(partial)[(size_t)b * CQ_ + q] = acc;
        }
    } else {  // b == NBLK_: histogram on 4 waves only; waves 4-15 exit now
        if (t >= 256) return;            // whole waves exit before any barrier
        __shared__ int lh[C_];
        for (int i = t; i < C_; i += 256) lh[i] = 0;
        __syncthreads();
        for (int i = t; i < B_; i += 256) atomicAdd(&lh[target[i]], 1);
        __syncthreads();
        for (int i = t; i < C_; i += 256) counts[i] = (float)lh[i];
    }
}

// ---- dispatch 2 (4 blocks x 1024): reduce 64 rows/exit (256 KB) -> out[e] --
__global__ __launch_bounds__(1024) void finalize_partial(
        const float* __restrict__ partial, const float* __restrict__ counts,
        float* __restrict__ out) {
    const int e = blockIdx.x, t = threadIdx.x;
    const int q  = t % CQ_;
    const int rg = t / CQ_;

    __shared__ float4 l2[RG_][CQ_];
    if (t < RG_ * CQ_) {
        const float4* p = reinterpret_cast<const float4*>(partial)
                        + (size_t)(e * RPE_ + rg * RPG_) * CQ_ + q;
        float4 a = make_float4(0.f, 0.f, 0.f, 0.f);
        #pragma unroll 8
        for (int k = 0; k < RPG_; ++k) {
            float4 v = p[(size_t)k * CQ_];
            a.x += v.x; a.y += v.y; a.z += v.z; a.w += v.w;
        }
        l2[rg][q] = a;
    }
    __syncthreads();

    float s = 0.f;
    if (t < CQ_) {
        float4 a = l2[0][t], b2 = l2[1][t], c = l2[2][t], d = l2[3][t];
        float4 cn = reinterpret_cast<const float4*>(counts)[t];
        s = fabsf(a.x + b2.x + c.x + d.x - cn.x)
          + fabsf(a.y + b2.y + c.y + d.y - cn.y)
          + fabsf(a.z + b2.z + c.z + d.z - cn.z)
          + fabsf(a.w + b2.w + c.w + d.w - cn.w);
    }
    #pragma unroll
    for (int off = 32; off > 0; off >>= 1) s += __shfl_down(s, off);
    __shared__ float red[16];
    if ((t & 63) == 0) red[t >> 6] = s;
    __syncthreads();
    if (t == 0) {
        float tot = 0.f;
        #pragma unroll
        for (int w = 0; w < 16; ++w) tot += red[w];
        out[e] = tot / ((float)B_ * (float)C_);
    }
}

extern "C" void kernel_launch(void* const* d_in, const int* in_sizes, int n_in,
                              void* d_out, int out_size, void* d_ws, size_t ws_size,
                              hipStream_t stream) {
    const float* logits = (const float*)d_in[0];
    const int*   target = (const int*)d_in[1];
    float* out  = (float*)d_out;
    float* part = (float*)d_ws;
    float* cnts = (float*)((char*)d_ws + COUNTS_OFF);

    hipLaunchKernelGGL(colsum_hist, dim3(NBLK_ + 1), dim3(1024), 0, stream,
                       logits, target, part, cnts);
    hipLaunchKernelGGL(finalize_partial, dim3(E_), dim3(1024), 0, stream,
                       part, cnts, out);
}

// Round 17
// 28.487 us; speedup vs baseline: 1.1920x; 1.1920x over previous
//
#include <hip/hip_runtime.h>

// logits: [E=4, B=8192, C=1000] f32 (131 MB, memory-bound), target: [B] i32,
// out: [E] f32.  loss[e] = (1/(B*C)) * sum_c |colsum(logits[e])[c] - hist(target)[c]|
//
// Measured structure decisions (final):
//  - coop grid.sync: ~100us/sync (R6) -> never.
//  - ticket/fence single-dispatch handoff: nondeterministic (R8 tripwire) -> never.
//  - EACH extra dispatch costs ~4-6us (R11) -> exactly 2 dispatches.
//  - hist in colsum block 0 serializes (R10) -> dedicated extra block.
//  - hist block must be FULL-SIZE (1024 thr): R16 shrank it to 4 waves and it
//    became the dispatch-1 critical path (28.5 -> 33.95us). 8 iters/thread
//    finishes inside the stream's shadow; CU-sharing costs <= 0.6us.
//  - partial rows cost tail time (R7 vs R14) -> 256 rows (1 MB).
//  - barriers must be block-uniform (R12 NaN).
//  - occupancy exhausted: 8 w/CU (R14, 29.1) vs 16 w/CU (R15, 28.5).
// Budget at 28.5us: stream ~21-22us (131MB, 7.2TB/s fill-ceiling, partial L3
// service) + ~4-5us dispatch gap + ~2us finalize -> structural floor.
constexpr int E_  = 4;
constexpr int B_  = 8192;
constexpr int C_  = 1000;
constexpr int CQ_ = C_ / 4;             // 250 float4 column-quads
constexpr int NB_ = 128;                // batch rows per colsum block
constexpr int CREWS_ = 4;               // 250-lane crews per block
constexpr int RPC_   = NB_ / CREWS_;    // 32 rows per crew
constexpr int NBLK_  = E_ * B_ / NB_;   // 256 colsum blocks (1/CU, 16 waves/CU)
constexpr int RPE_   = B_ / NB_;        // 64 partial rows per exit
constexpr int RG_    = 4;               // row-groups in finalize
constexpr int RPG_   = RPE_ / RG_;      // 16 rows per row-group

// ws: partial[NBLK_][C_] f32 | counts[C_] f32
constexpr size_t PARTIAL_BYTES = (size_t)NBLK_ * C_ * sizeof(float); // 1,024,000
constexpr size_t COUNTS_OFF    = PARTIAL_BYTES;

// ---- dispatch 1 (257 blocks x 1024): 256 colsum blocks + 1 hist block ------
// Colsum block: q = t%250, h = t/250 in {0..3} active, t>=1000 idle. Crew h
// sums rows [b*128 + h*32, +32) of its column-quad (coalesced float4). Crews
// 1-3 stage to LDS; ONE uniform barrier; crew 0 combines + stores partial row.
__global__ __launch_bounds__(1024) void colsum_hist(
        const float* __restrict__ logits, const int* __restrict__ target,
        float* __restrict__ partial, float* __restrict__ counts) {
    const int b = blockIdx.x, t = threadIdx.x;

    if (b < NBLK_) {
        __shared__ float4 comb[CREWS_ - 1][CQ_];
        const int q = t % CQ_;
        const int h = t / CQ_;
        float4 acc = make_float4(0.f, 0.f, 0.f, 0.f);
        if (h < CREWS_) {
            const float4* base = reinterpret_cast<const float4*>(logits)
                               + (size_t)(b * NB_ + h * RPC_) * CQ_ + q;
            #pragma unroll 8
            for (int r = 0; r < RPC_; ++r) {
                float4 v = base[(size_t)r * CQ_];
                acc.x += v.x; acc.y += v.y; acc.z += v.z; acc.w += v.w;
            }
        }
        if (h >= 1 && h < CREWS_) comb[h - 1][q] = acc;
        __syncthreads();                 // single block-uniform barrier
        if (h == 0) {
            #pragma unroll
            for (int j = 0; j < CREWS_ - 1; ++j) {
                float4 o = comb[j][q];
                acc.x += o.x; acc.y += o.y; acc.z += o.z; acc.w += o.w;
            }
            reinterpret_cast<float4*>(partial)[(size_t)b * CQ_ + q] = acc;
        }
    } else {  // b == NBLK_: histogram block (own uniform barriers)
        __shared__ int lh[C_];
        for (int i = t; i < C_; i += 1024) lh[i] = 0;
        __syncthreads();
        for (int i = t; i < B_; i += 1024) atomicAdd(&lh[target[i]], 1);
        __syncthreads();
        for (int i = t; i < C_; i += 1024) counts[i] = (float)lh[i];
    }
}

// ---- dispatch 2 (4 blocks x 1024): reduce 64 rows/exit (256 KB) -> out[e] --
__global__ __launch_bounds__(1024) void finalize_partial(
        const float* __restrict__ partial, const float* __restrict__ counts,
        float* __restrict__ out) {
    const int e = blockIdx.x, t = threadIdx.x;
    const int q  = t % CQ_;
    const int rg = t / CQ_;

    __shared__ float4 l2[RG_][CQ_];
    if (t < RG_ * CQ_) {
        const float4* p = reinterpret_cast<const float4*>(partial)
                        + (size_t)(e * RPE_ + rg * RPG_) * CQ_ + q;
        float4 a = make_float4(0.f, 0.f, 0.f, 0.f);
        #pragma unroll 8
        for (int k = 0; k < RPG_; ++k) {
            float4 v = p[(size_t)k * CQ_];
            a.x += v.x; a.y += v.y; a.z += v.z; a.w += v.w;
        }
        l2[rg][q] = a;
    }
    __syncthreads();

    float s = 0.f;
    if (t < CQ_) {
        float4 a = l2[0][t], b2 = l2[1][t], c = l2[2][t], d = l2[3][t];
        float4 cn = reinterpret_cast<const float4*>(counts)[t];
        s = fabsf(a.x + b2.x + c.x + d.x - cn.x)
          + fabsf(a.y + b2.y + c.y + d.y - cn.y)
          + fabsf(a.z + b2.z + c.z + d.z - cn.z)
          + fabsf(a.w + b2.w + c.w + d.w - cn.w);
    }
    #pragma unroll
    for (int off = 32; off > 0; off >>= 1) s += __shfl_down(s, off);
    __shared__ float red[16];
    if ((t & 63) == 0) red[t >> 6] = s;
    __syncthreads();
    if (t == 0) {
        float tot = 0.f;
        #pragma unroll
        for (int w = 0; w < 16; ++w) tot += red[w];
        out[e] = tot / ((float)B_ * (float)C_);
    }
}

extern "C" void kernel_launch(void* const* d_in, const int* in_sizes, int n_in,
                              void* d_out, int out_size, void* d_ws, size_t ws_size,
                              hipStream_t stream) {
    const float* logits = (const float*)d_in[0];
    const int*   target = (const int*)d_in[1];
    float* out  = (float*)d_out;
    float* part = (float*)d_ws;
    float* cnts = (float*)((char*)d_ws + COUNTS_OFF);

    hipLaunchKernelGGL(colsum_hist, dim3(NBLK_ + 1), dim3(1024), 0, stream,
                       logits, target, part, cnts);
    hipLaunchKernelGGL(finalize_partial, dim3(E_), dim3(1024), 0, stream,
                       part, cnts, out);
}